// Round 1
// baseline (301.891 us; speedup 1.0000x reference)
//
#include <hip/hip_runtime.h>

typedef unsigned short u16;
typedef unsigned int u32;
typedef __attribute__((ext_vector_type(8))) short short8;
typedef __attribute__((ext_vector_type(4))) float f32x4;

__device__ __forceinline__ u16 f2bf(float f) {
  u32 u = __builtin_bit_cast(u32, f);
  u += 0x7fffu + ((u >> 16) & 1u);
  return (u16)(u >> 16);
}

__device__ __forceinline__ void async16(const void* g, void* l) {
  __builtin_amdgcn_global_load_lds(
      (const __attribute__((address_space(1))) u32*)g,
      (__attribute__((address_space(3))) u32*)l, 16, 0, 0);
}

// ---------------- weight transpose: in (K x N) f32 -> outT (N x K) bf16 ----
// scaleN: rows n < scaleN get * 0.125 (folds q-scale into w_qkv)
__global__ __launch_bounds__(256) void k_wt(const float* __restrict__ in,
                                            u16* __restrict__ outT,
                                            int K, int N, int scaleN) {
  const int bid = blockIdx.x;
  const int ntiles = N >> 5;
  const int nt = bid % ntiles, kt = bid / ntiles;
  const int n0 = nt << 5, k0 = kt << 5;
  __shared__ float tile[32][33];
  const int t = threadIdx.x;
#pragma unroll
  for (int i = 0; i < 4; ++i) {
    const int e = t + i * 256, r = e >> 5, c = e & 31;  // r: k, c: n
    tile[c][r] = in[(size_t)(k0 + r) * N + n0 + c];
  }
  __syncthreads();
#pragma unroll
  for (int i = 0; i < 4; ++i) {
    const int e = t + i * 256, r = e >> 5, c = e & 31;  // r: n, c: k
    float v = tile[r][c];
    if (n0 + r < scaleN) v *= 0.125f;
    outT[(size_t)(n0 + r) * K + k0 + c] = f2bf(v);
  }
}

// ---------------- x transpose: (b,c,f,h,w) f32 -> XT[(b,f,y,x)][c] bf16 ----
__global__ __launch_bounds__(256) void k_xt(const float* __restrict__ x,
                                            u16* __restrict__ XT) {
  const int bid = blockIdx.x;
  const int plane = bid & 31;   // b*16 + f
  const int rest = bid >> 5;
  const int mt = rest & 31, ct = rest >> 5;
  const int bb = plane >> 4, f = plane & 15;
  const int m0 = mt << 5, c0 = ct << 5;
  __shared__ float tile[32][33];
  const int t = threadIdx.x;
#pragma unroll
  for (int i = 0; i < 4; ++i) {
    const int e = t + i * 256, r = e >> 5, c = e & 31;  // r: ch, c: m
    tile[c][r] = x[((size_t)((bb * 512 + c0 + r) * 16 + f)) * 1024 + m0 + c];
  }
  __syncthreads();
#pragma unroll
  for (int i = 0; i < 4; ++i) {
    const int e = t + i * 256, r = e >> 5, c = e & 31;  // r: m, c: ch
    XT[((size_t)(plane * 1024 + m0 + r)) * 512 + c0 + c] = f2bf(tile[r][c]);
  }
}

// ---------------- fused QKV GEMM + attention ------------------------------
// block: 4 sites (M=64), 4 waves. Per head: GEMM M=64,N=192,K=512 (MFMA),
// qkv -> LDS fp32, wave w does attention for site w, writes attn_out bf16.
__global__ __launch_bounds__(256) void k_qkv_attn(const u16* __restrict__ XT,
                                                  const u16* __restrict__ WQ,
                                                  const float* __restrict__ pos_bias,
                                                  u16* __restrict__ AO) {
  const int tid = threadIdx.x;
  const int w = tid >> 6, lane = tid & 63;
  const int c15 = lane & 15, quad = lane >> 4;
  const int grp = blockIdx.x;          // 512 blocks
  const int b = grp >> 8, m0 = (grp & 255) << 2;

  __shared__ u16 Ast[64][64];          // A stage, BK=64, XOR-swizzled cols
  __shared__ float qkv_s[4][16][196];  // [site][f][0:64 q | 64:128 k | 128:192 v]
  __shared__ float p_s[4][16][17];     // softmax probs

  const int lr = lane >> 3, lcb = lane & 7;
  const int i_ = lane >> 2, j4 = lane & 3;
  const int dg = lane & 3;

  for (int hd = 0; hd < 8; ++hd) {
    f32x4 acc[3][4];
#pragma unroll
    for (int c = 0; c < 3; ++c)
#pragma unroll
      for (int mt = 0; mt < 4; ++mt) acc[c][mt] = f32x4{0.f, 0.f, 0.f, 0.f};

    const u16* bq = WQ + (size_t)(hd * 64 + w * 16 + c15) * 512;
    const u16* bk = bq + (size_t)512 * 512;
    const u16* bv = bq + (size_t)1024 * 512;

    for (int kk = 0; kk < 8; ++kk) {
      __syncthreads();  // prev readers of Ast done
      const int kc = kk << 6;
#pragma unroll
      for (int t2 = 0; t2 < 2; ++t2) {
        const int f = t2 * 8 + lr;  // row within site = f; site = w
        const int swcol = kc + ((lcb ^ (f & 7)) << 3);
        async16(XT + ((size_t)(b * 16384 + f * 1024 + m0 + w)) * 512 + swcol,
                &Ast[w * 16 + t2 * 8][0]);
      }
      __syncthreads();
#pragma unroll
      for (int half = 0; half < 2; ++half) {
        short8 af[4];
#pragma unroll
        for (int mt = 0; mt < 4; ++mt) {
          const int row = mt * 16 + c15;
          const int swz = (((half << 2) + quad) ^ (row & 7)) << 3;
          af[mt] = *(const short8*)&Ast[row][swz];
        }
        const int kof = kc + half * 32 + quad * 8;
        const short8 fq = *(const short8*)(bq + kof);
        const short8 fk = *(const short8*)(bk + kof);
        const short8 fv = *(const short8*)(bv + kof);
#pragma unroll
        for (int mt = 0; mt < 4; ++mt) {
          acc[0][mt] = __builtin_amdgcn_mfma_f32_16x16x32_bf16(af[mt], fq, acc[0][mt], 0, 0, 0);
          acc[1][mt] = __builtin_amdgcn_mfma_f32_16x16x32_bf16(af[mt], fk, acc[1][mt], 0, 0, 0);
          acc[2][mt] = __builtin_amdgcn_mfma_f32_16x16x32_bf16(af[mt], fv, acc[2][mt], 0, 0, 0);
        }
      }
    }
    __syncthreads();  // prev head's attention reads of qkv_s/p_s done
    // C/D layout: row(m-in-tile)=quad*4+r, col(n-in-tile)=c15; site = mt
#pragma unroll
    for (int c = 0; c < 3; ++c)
#pragma unroll
      for (int mt = 0; mt < 4; ++mt)
#pragma unroll
        for (int r = 0; r < 4; ++r)
          qkv_s[mt][quad * 4 + r][c * 64 + w * 16 + c15] = acc[c][mt][r];
    __syncthreads();

    // ---- attention for site w: sim + softmax. lane: i = i_, j in {j4+4p} --
    float s0 = 0.f, s1 = 0.f, s2 = 0.f, s3 = 0.f;
#pragma unroll 4
    for (int d4 = 0; d4 < 16; ++d4) {
      const float4 qv = *(const float4*)&qkv_s[w][i_][d4 * 4];
      const float4 k0v = *(const float4*)&qkv_s[w][j4][64 + d4 * 4];
      const float4 k1v = *(const float4*)&qkv_s[w][4 + j4][64 + d4 * 4];
      const float4 k2v = *(const float4*)&qkv_s[w][8 + j4][64 + d4 * 4];
      const float4 k3v = *(const float4*)&qkv_s[w][12 + j4][64 + d4 * 4];
      s0 += qv.x * k0v.x + qv.y * k0v.y + qv.z * k0v.z + qv.w * k0v.w;
      s1 += qv.x * k1v.x + qv.y * k1v.y + qv.z * k1v.z + qv.w * k1v.w;
      s2 += qv.x * k2v.x + qv.y * k2v.y + qv.z * k2v.z + qv.w * k2v.w;
      s3 += qv.x * k3v.x + qv.y * k3v.y + qv.z * k3v.z + qv.w * k3v.w;
    }
    const float* pb = pos_bias + hd * 256 + i_ * 16;
    s0 += pb[j4]; s1 += pb[4 + j4]; s2 += pb[8 + j4]; s3 += pb[12 + j4];
    float mx = fmaxf(fmaxf(s0, s1), fmaxf(s2, s3));
    mx = fmaxf(mx, __shfl_xor(mx, 1));
    mx = fmaxf(mx, __shfl_xor(mx, 2));
    const float e0 = __expf(s0 - mx), e1 = __expf(s1 - mx);
    const float e2 = __expf(s2 - mx), e3 = __expf(s3 - mx);
    float sum = e0 + e1 + e2 + e3;
    sum += __shfl_xor(sum, 1);
    sum += __shfl_xor(sum, 2);
    const float inv = 1.0f / sum;
    p_s[w][i_][j4] = e0 * inv;
    p_s[w][i_][4 + j4] = e1 * inv;
    p_s[w][i_][8 + j4] = e2 * inv;
    p_s[w][i_][12 + j4] = e3 * inv;
    __syncthreads();

    // ---- out = P @ V. lane: i = i_, d-range = dg*16..+16 -----------------
    float4 o0 = make_float4(0.f, 0.f, 0.f, 0.f);
    float4 o1 = make_float4(0.f, 0.f, 0.f, 0.f);
    float4 o2 = make_float4(0.f, 0.f, 0.f, 0.f);
    float4 o3 = make_float4(0.f, 0.f, 0.f, 0.f);
#pragma unroll 4
    for (int j = 0; j < 16; ++j) {
      const float pij = p_s[w][i_][j];
      const float4 v0 = *(const float4*)&qkv_s[w][j][128 + dg * 16];
      const float4 v1 = *(const float4*)&qkv_s[w][j][128 + dg * 16 + 4];
      const float4 v2 = *(const float4*)&qkv_s[w][j][128 + dg * 16 + 8];
      const float4 v3 = *(const float4*)&qkv_s[w][j][128 + dg * 16 + 12];
      o0.x += pij * v0.x; o0.y += pij * v0.y; o0.z += pij * v0.z; o0.w += pij * v0.w;
      o1.x += pij * v1.x; o1.y += pij * v1.y; o1.z += pij * v1.z; o1.w += pij * v1.w;
      o2.x += pij * v2.x; o2.y += pij * v2.y; o2.z += pij * v2.z; o2.w += pij * v2.w;
      o3.x += pij * v3.x; o3.y += pij * v3.y; o3.z += pij * v3.z; o3.w += pij * v3.w;
    }
    union { u16 us[16]; uint4 q[2]; } pk;
    pk.us[0] = f2bf(o0.x); pk.us[1] = f2bf(o0.y); pk.us[2] = f2bf(o0.z); pk.us[3] = f2bf(o0.w);
    pk.us[4] = f2bf(o1.x); pk.us[5] = f2bf(o1.y); pk.us[6] = f2bf(o1.z); pk.us[7] = f2bf(o1.w);
    pk.us[8] = f2bf(o2.x); pk.us[9] = f2bf(o2.y); pk.us[10] = f2bf(o2.z); pk.us[11] = f2bf(o2.w);
    pk.us[12] = f2bf(o3.x); pk.us[13] = f2bf(o3.y); pk.us[14] = f2bf(o3.z); pk.us[15] = f2bf(o3.w);
    uint4* dst = (uint4*)(AO + ((size_t)(b * 16384 + i_ * 1024 + m0 + w)) * 512 +
                          hd * 64 + dg * 16);
    dst[0] = pk.q[0];
    dst[1] = pk.q[1];
  }
}

// ---------------- out projection GEMM + transposed store ------------------
struct K2St { u16 A[128][64]; u16 B[128][64]; };
union K2Sm { K2St st; float C[64][130]; };

__global__ __launch_bounds__(256) void k_proj(const u16* __restrict__ AO,
                                              const u16* __restrict__ WO,
                                              float* __restrict__ out) {
  const int tid = threadIdx.x, w = tid >> 6, lane = tid & 63;
  const int c15 = lane & 15, quad = lane >> 4;
  const int bid = blockIdx.x;          // 1024 blocks
  const int nb = bid & 3, mb = bid >> 2;
  const int m0 = mb << 7, n0 = nb << 7;
  const int b = m0 >> 14, mloc = m0 & 16383;
  __shared__ K2Sm sm;
  f32x4 acc[8][2];
#pragma unroll
  for (int mt = 0; mt < 8; ++mt) {
    acc[mt][0] = f32x4{0.f, 0.f, 0.f, 0.f};
    acc[mt][1] = f32x4{0.f, 0.f, 0.f, 0.f};
  }
  const int lr = lane >> 3, lcb = lane & 7;
  for (int kk = 0; kk < 8; ++kk) {
    __syncthreads();
    const int kc = kk << 6;
#pragma unroll
    for (int t2 = 0; t2 < 4; ++t2) {
      const int r = w * 32 + t2 * 8 + lr;
      const int swcol = kc + ((lcb ^ (r & 7)) << 3);
      async16(AO + (size_t)(m0 + r) * 512 + swcol, &sm.st.A[w * 32 + t2 * 8][0]);
      async16(WO + (size_t)(n0 + r) * 512 + swcol, &sm.st.B[w * 32 + t2 * 8][0]);
    }
    __syncthreads();
#pragma unroll
    for (int half = 0; half < 2; ++half) {
      short8 af[8], bt[2];
#pragma unroll
      for (int mt = 0; mt < 8; ++mt) {
        const int row = mt * 16 + c15;
        const int swz = (((half << 2) + quad) ^ (row & 7)) << 3;
        af[mt] = *(const short8*)&sm.st.A[row][swz];
      }
#pragma unroll
      for (int nt = 0; nt < 2; ++nt) {
        const int row = w * 32 + nt * 16 + c15;
        const int swz = (((half << 2) + quad) ^ (row & 7)) << 3;
        bt[nt] = *(const short8*)&sm.st.B[row][swz];
      }
#pragma unroll
      for (int mt = 0; mt < 8; ++mt) {
        acc[mt][0] = __builtin_amdgcn_mfma_f32_16x16x32_bf16(af[mt], bt[0], acc[mt][0], 0, 0, 0);
        acc[mt][1] = __builtin_amdgcn_mfma_f32_16x16x32_bf16(af[mt], bt[1], acc[mt][1], 0, 0, 0);
      }
    }
  }
  __syncthreads();
#pragma unroll
  for (int h = 0; h < 2; ++h) {
#pragma unroll
    for (int mt2 = 0; mt2 < 4; ++mt2) {
      const int mt = h * 4 + mt2;
#pragma unroll
      for (int nt = 0; nt < 2; ++nt)
#pragma unroll
        for (int r = 0; r < 4; ++r)
          sm.C[mt2 * 16 + quad * 4 + r][w * 32 + nt * 16 + c15] = acc[mt][nt][r];
    }
    __syncthreads();
    for (int jj = 0; jj < 32; ++jj) {
      const int ch = n0 + w * 32 + jj;
      out[(size_t)(b * 512 + ch) * 16384 + mloc + h * 64 + lane] = sm.C[lane][w * 32 + jj];
    }
    __syncthreads();
  }
}

extern "C" void kernel_launch(void* const* d_in, const int* in_sizes, int n_in,
                              void* d_out, int out_size, void* d_ws, size_t ws_size,
                              hipStream_t stream) {
  const float* x = (const float*)d_in[0];
  const float* pos_bias = (const float*)d_in[1];
  const float* w_qkv = (const float*)d_in[2];
  const float* w_out = (const float*)d_in[3];
  float* out = (float*)d_out;
  char* ws = (char*)d_ws;
  // ws layout (bytes): XT 33554432 | AO 33554432 | WQ 1572864 | WO 524288
  u16* XT = (u16*)(ws);
  u16* AO = (u16*)(ws + (size_t)33554432);
  u16* WQ = (u16*)(ws + (size_t)67108864);
  u16* WO = (u16*)(ws + (size_t)68681728);

  hipLaunchKernelGGL(k_wt, dim3(768), dim3(256), 0, stream, w_qkv, WQ, 512, 1536, 512);
  hipLaunchKernelGGL(k_wt, dim3(256), dim3(256), 0, stream, w_out, WO, 512, 512, 0);
  hipLaunchKernelGGL(k_xt, dim3(16384), dim3(256), 0, stream, x, XT);
  hipLaunchKernelGGL(k_qkv_attn, dim3(512), dim3(256), 0, stream, XT, WQ, pos_bias, AO);
  hipLaunchKernelGGL(k_proj, dim3(1024), dim3(256), 0, stream, AO, WO, out);
}